// Round 2
// baseline (476.529 us; speedup 1.0000x reference)
//
#include <hip/hip_runtime.h>
#include <math.h>

// Problem constants (fixed by setup_inputs)
#define N_TOK 16384   // B*S
#define D_DIM 2048
#define H_DIM 256
#define E_NUM 5
#define R_DIM 16
#define ER 80         // E*R

#define NCT 21        // 16 W1 col-tiles + 5 A' col-tiles (16 cols each)
#define KSTEPS 32     // 2048 / 64  (BK = 64)

typedef _Float16 half8 __attribute__((ext_vector_type(8)));
typedef float f32x4 __attribute__((ext_vector_type(4)));

// ---------------------------------------------------------------------------
// pack_w: W1[2048][256] and A'[2048][80] (A'[d][e*16+r] = A[e][d][r]) -> f16
// hi/lo fragment-linear arrays (layout unchanged from round 1):
//   Wp[((ct*64+kg32)*64+l)*8+j] = W[kg32*32 + (l>>4)*8 + j][ct*16 + (l&15)]
// Also zeroes the logits accumulator (xgemm atomically adds into it).
// ---------------------------------------------------------------------------
__global__ __launch_bounds__(256) void pack_w_kernel(
    const float* __restrict__ W1, const float* __restrict__ A,
    _Float16* __restrict__ Whi, _Float16* __restrict__ Wlo,
    float* __restrict__ logits) {
  const int idx = blockIdx.x * 256 + threadIdx.x;  // 21*64*64 = 86016 exact
  if (idx < N_TOK * E_NUM) logits[idx] = 0.f;      // 81920 < 86016
  const int lane = idx & 63;
  const int kgct = idx >> 6;              // ct*64 + kg32, 0..1343
  const int kg = kgct & 63;
  const int ct = kgct >> 6;               // 0..20
  const int k0 = kg * 32 + ((lane >> 4) << 3);
  const int par = lane & 15;
  float v[8];
  if (ct < 16) {
    const int col = ct * 16 + par;
#pragma unroll
    for (int j = 0; j < 8; ++j) v[j] = W1[(size_t)(k0 + j) * H_DIM + col];
  } else {
    const float* Ae = A + (size_t)(ct - 16) * D_DIM * R_DIM;
#pragma unroll
    for (int j = 0; j < 8; ++j) v[j] = Ae[(size_t)(k0 + j) * R_DIM + par];
  }
  half8 hv, lv;
#pragma unroll
  for (int j = 0; j < 8; ++j) {
    const _Float16 hh = (_Float16)v[j];
    hv[j] = hh;
    lv[j] = (_Float16)(v[j] - (float)hh);
  }
  ((half8*)Whi)[(size_t)kgct * 64 + lane] = hv;
  ((half8*)Wlo)[(size_t)kgct * 64 + lane] = lv;
}

// ---------------------------------------------------------------------------
// xgemm: grid (N_TOK/64, 3). MFMA 16x16x32 f16, split-f16 3-product.
//   y in {0,1}: computes silu(x@W1+b1) cols [y*128, +128) IN REGISTERS and
//               immediately projects through W2: atomicAdd partial logits.
//               (h is never materialized — saves 32 MB of HBM traffic and
//               the entire route kernel.)
//   y == 2   : P[:, 0..79] = x @ A'   (stored fp32; scaled later in combine)
// BK=64 (32 K-steps, half the barriers of round 1). x staged fp32->f16 hi/lo
// in LDS, double buffered. XOR swizzle row' = row ^ kq: staging writes from
// lanes 0..7 then cover all 8 bank-groups (was 4-way conflict = 9.4M cycles),
// and fragment reads remain permuted-contiguous 256B chunks (conflict-free).
// ---------------------------------------------------------------------------
__global__ __launch_bounds__(256, 3) void xgemm_kernel(
    const float* __restrict__ x, const float* __restrict__ b1,
    const _Float16* __restrict__ Whi, const _Float16* __restrict__ Wlo,
    const float* __restrict__ W2, float* __restrict__ logits,
    float* __restrict__ P) {
  __shared__ _Float16 lds[2][2][8][64][8];  // [buf][hi/lo][kq][row'][8] = 32 KB
  __shared__ float w2s[H_DIM * E_NUM];      // 5 KB, epilogue only
  const int t = threadIdx.x;
  const int tok0 = blockIdx.x * 64;
  const int y = blockIdx.y;
  const int lane = t & 63;
  const int w = t >> 6;          // wave 0..3
  const int sr = t >> 2;         // staging row 0..63
  const int q = t & 3;           // staging k-16-chunk 0..3
  const int lq = lane >> 4;      // lane k-quarter
  const int lp = lane & 15;      // lane parallel index

  const float* xrow = x + (size_t)(tok0 + sr) * D_DIM + (q << 4);

  // prologue: stage kg=0 into buf 0
  {
    float xv[16];
    *(float4*)&xv[0] = *(const float4*)(xrow);
    *(float4*)&xv[4] = *(const float4*)(xrow + 4);
    *(float4*)&xv[8] = *(const float4*)(xrow + 8);
    *(float4*)&xv[12] = *(const float4*)(xrow + 12);
#pragma unroll
    for (int hf = 0; hf < 2; ++hf) {
      half8 hv, lv;
#pragma unroll
      for (int j = 0; j < 8; ++j) {
        const float v = xv[(hf << 3) + j];
        const _Float16 hh = (_Float16)v;
        hv[j] = hh;
        lv[j] = (_Float16)(v - (float)hh);
      }
      const int kq = (q << 1) + hf;
      *(half8*)&lds[0][0][kq][sr ^ kq][0] = hv;
      *(half8*)&lds[0][1][kq][sr ^ kq][0] = lv;
    }
  }

  const half8* WH = (const half8*)Whi;
  const half8* WL = (const half8*)Wlo;

  if (y < 2) {
    f32x4 acc[4][2];
#pragma unroll
    for (int i = 0; i < 4; ++i)
#pragma unroll
      for (int j = 0; j < 2; ++j) acc[i][j] = (f32x4)0.f;
    const int ctg0 = (y << 3) + (w << 1);  // wave owns 2 col-tiles
    int cur = 0;
    for (int kg = 0; kg < KSTEPS; ++kg) {
      __syncthreads();
      float xv[16];
      const bool more = (kg < KSTEPS - 1);
      if (more) {  // prefetch next x chunk early (64 floats / 4 lanes / row)
        const float* src = xrow + (kg + 1) * 64;
        *(float4*)&xv[0] = *(const float4*)(src);
        *(float4*)&xv[4] = *(const float4*)(src + 4);
        *(float4*)&xv[8] = *(const float4*)(src + 8);
        *(float4*)&xv[12] = *(const float4*)(src + 12);
      }
      half8 bh[2][2], bl[2][2];
#pragma unroll
      for (int ct = 0; ct < 2; ++ct)
#pragma unroll
        for (int h2 = 0; h2 < 2; ++h2) {
          const size_t wo = ((size_t)(ctg0 + ct) * 64 + (kg << 1) + h2) * 64 + lane;
          bh[ct][h2] = WH[wo];
          bl[ct][h2] = WL[wo];
        }
#pragma unroll
      for (int h2 = 0; h2 < 2; ++h2) {
        const int kq = (h2 << 2) + lq;
#pragma unroll
        for (int rt = 0; rt < 4; ++rt) {
          const int r = ((rt << 4) + lp) ^ kq;
          const half8 ah = *(const half8*)&lds[cur][0][kq][r][0];
          const half8 al = *(const half8*)&lds[cur][1][kq][r][0];
#pragma unroll
          for (int ct = 0; ct < 2; ++ct) {
            acc[rt][ct] = __builtin_amdgcn_mfma_f32_16x16x32_f16(al, bh[ct][h2], acc[rt][ct], 0, 0, 0);
            acc[rt][ct] = __builtin_amdgcn_mfma_f32_16x16x32_f16(ah, bl[ct][h2], acc[rt][ct], 0, 0, 0);
            acc[rt][ct] = __builtin_amdgcn_mfma_f32_16x16x32_f16(ah, bh[ct][h2], acc[rt][ct], 0, 0, 0);
          }
        }
      }
      if (more) {
#pragma unroll
        for (int hf = 0; hf < 2; ++hf) {
          half8 hv, lv;
#pragma unroll
          for (int j = 0; j < 8; ++j) {
            const float v = xv[(hf << 3) + j];
            const _Float16 hh = (_Float16)v;
            hv[j] = hh;
            lv[j] = (_Float16)(v - (float)hh);
          }
          const int kq = (q << 1) + hf;
          *(half8*)&lds[cur ^ 1][0][kq][sr ^ kq][0] = hv;
          *(half8*)&lds[cur ^ 1][1][kq][sr ^ kq][0] = lv;
        }
      }
      cur ^= 1;
    }
    // epilogue: silu in-register, project through W2, atomic partial logits.
    for (int i = t; i < H_DIM * E_NUM; i += 256) w2s[i] = W2[i];
    __syncthreads();
    const int colb = (y << 7) + (w << 5);
#pragma unroll
    for (int rt = 0; rt < 4; ++rt) {
      float pl[4][5];
#pragma unroll
      for (int rg = 0; rg < 4; ++rg)
#pragma unroll
        for (int e = 0; e < 5; ++e) pl[rg][e] = 0.f;
#pragma unroll
      for (int ct = 0; ct < 2; ++ct) {
        const int col = colb + (ct << 4) + lp;
        const float bb = b1[col];
        float w2c[5];
#pragma unroll
        for (int e = 0; e < 5; ++e) w2c[e] = w2s[col * 5 + e];
#pragma unroll
        for (int rg = 0; rg < 4; ++rg) {
          float v = acc[rt][ct][rg] + bb;
          v = v / (1.f + expf(-v));  // silu; h value, never stored
#pragma unroll
          for (int e = 0; e < 5; ++e) pl[rg][e] = fmaf(v, w2c[e], pl[rg][e]);
        }
      }
      // reduce the 16 col-lanes (lp) of each lq group
#pragma unroll
      for (int m = 1; m < 16; m <<= 1)
#pragma unroll
        for (int rg = 0; rg < 4; ++rg)
#pragma unroll
          for (int e = 0; e < 5; ++e) pl[rg][e] += __shfl_xor(pl[rg][e], m, 64);
      if (lp == 0) {
        const int row0 = tok0 + (rt << 4) + (lq << 2);
#pragma unroll
        for (int rg = 0; rg < 4; ++rg)
#pragma unroll
          for (int e = 0; e < 5; ++e)
            atomicAdd(&logits[(size_t)(row0 + rg) * E_NUM + e], pl[rg][e]);
      }
    }
  } else {
    // P path: wave owns 16 rows x all 80 cols (5 col-tiles)
    f32x4 acc[5];
#pragma unroll
    for (int j = 0; j < 5; ++j) acc[j] = (f32x4)0.f;
    int cur = 0;
    for (int kg = 0; kg < KSTEPS; ++kg) {
      __syncthreads();
      float xv[16];
      const bool more = (kg < KSTEPS - 1);
      if (more) {
        const float* src = xrow + (kg + 1) * 64;
        *(float4*)&xv[0] = *(const float4*)(src);
        *(float4*)&xv[4] = *(const float4*)(src + 4);
        *(float4*)&xv[8] = *(const float4*)(src + 8);
        *(float4*)&xv[12] = *(const float4*)(src + 12);
      }
      half8 bh[5][2], bl[5][2];
#pragma unroll
      for (int ct = 0; ct < 5; ++ct)
#pragma unroll
        for (int h2 = 0; h2 < 2; ++h2) {
          const size_t wo = ((size_t)(16 + ct) * 64 + (kg << 1) + h2) * 64 + lane;
          bh[ct][h2] = WH[wo];
          bl[ct][h2] = WL[wo];
        }
#pragma unroll
      for (int h2 = 0; h2 < 2; ++h2) {
        const int kq = (h2 << 2) + lq;
        const int r = ((w << 4) + lp) ^ kq;
        const half8 ah = *(const half8*)&lds[cur][0][kq][r][0];
        const half8 al = *(const half8*)&lds[cur][1][kq][r][0];
#pragma unroll
        for (int ct = 0; ct < 5; ++ct) {
          acc[ct] = __builtin_amdgcn_mfma_f32_16x16x32_f16(al, bh[ct][h2], acc[ct], 0, 0, 0);
          acc[ct] = __builtin_amdgcn_mfma_f32_16x16x32_f16(ah, bl[ct][h2], acc[ct], 0, 0, 0);
          acc[ct] = __builtin_amdgcn_mfma_f32_16x16x32_f16(ah, bh[ct][h2], acc[ct], 0, 0, 0);
        }
      }
      if (more) {
#pragma unroll
        for (int hf = 0; hf < 2; ++hf) {
          half8 hv, lv;
#pragma unroll
          for (int j = 0; j < 8; ++j) {
            const float v = xv[(hf << 3) + j];
            const _Float16 hh = (_Float16)v;
            hv[j] = hh;
            lv[j] = (_Float16)(v - (float)hh);
          }
          const int kq = (q << 1) + hf;
          *(half8*)&lds[cur ^ 1][0][kq][sr ^ kq][0] = hv;
          *(half8*)&lds[cur ^ 1][1][kq][sr ^ kq][0] = lv;
        }
      }
      cur ^= 1;
    }
#pragma unroll
    for (int ct = 0; ct < 5; ++ct)
#pragma unroll
      for (int rg = 0; rg < 4; ++rg) {
        const int row = tok0 + (w << 4) + (lq << 2) + rg;
        P[(size_t)row * ER + (ct << 4) + lp] = acc[ct][rg];
      }
  }
}

// ---------------------------------------------------------------------------
// combine: out = base + (scaled P)[N,80] @ B[80,2048].  Route decision fused:
// a 64-thread prologue reads logits, computes top-2 + normalized scales
// (8x redundant per token across col-split blocks — trivially cheap), then P
// is staged to LDS pre-scaled. Inner loop reads P via uniform-address
// ds_read_b128 (broadcast, conflict-free) instead of round 1's 320 serial
// scalar loads with lgkm waits.
// ---------------------------------------------------------------------------
__global__ __launch_bounds__(256) void combine_kernel(
    const float* __restrict__ P, const float* __restrict__ Bm,
    const float* __restrict__ base, const float* __restrict__ logits,
    const float* __restrict__ b2, float* __restrict__ out) {
  __shared__ float Pl[64][80];  // pre-scaled P tile, 20 KB
  __shared__ float sc[64][5];   // per-token per-expert scale
  const int t = threadIdx.x;
  const int wg = __builtin_amdgcn_readfirstlane(t >> 6);  // wave-uniform
  const int c4 = ((blockIdx.x & 7) << 8) + ((t & 63) << 2);
  const int tokb = (blockIdx.x >> 3) << 6;

  if (t < 64) {
    float lg[5];
#pragma unroll
    for (int e = 0; e < 5; ++e)
      lg[e] = logits[(size_t)(tokb + t) * E_NUM + e] + b2[e];
    int e0 = 0;
#pragma unroll
    for (int e = 1; e < 5; ++e) if (lg[e] > lg[e0]) e0 = e;
    int e1 = (e0 == 0) ? 1 : 0;
#pragma unroll
    for (int e = 0; e < 5; ++e) if (e != e0 && lg[e] > lg[e1]) e1 = e;
    const float qq = expf(lg[e1] - lg[e0]);  // <= 1, stable
    const float s0 = 2.f / (1.f + qq);       // SCALING * w0_normalized
    const float s1 = qq * s0;                // SCALING * w1_normalized
#pragma unroll
    for (int e = 0; e < 5; ++e)
      sc[t][e] = (e == e0) ? s0 : ((e == e1) ? s1 : 0.f);
  }
  __syncthreads();
  {  // stage P, scaled: thread t covers row t/4, 20-float chunk (t&3)
    const int row = t >> 2;
    const int off = (t & 3) * 20;
    const float* prow = P + (size_t)(tokb + row) * ER + off;
#pragma unroll
    for (int j = 0; j < 5; ++j) {
      float4 v = *(const float4*)(prow + (j << 2));
      v.x *= sc[row][(off + (j << 2) + 0) >> 4];
      v.y *= sc[row][(off + (j << 2) + 1) >> 4];
      v.z *= sc[row][(off + (j << 2) + 2) >> 4];
      v.w *= sc[row][(off + (j << 2) + 3) >> 4];
      *(float4*)&Pl[row][off + (j << 2)] = v;
    }
  }
  __syncthreads();

  float4 acc[16];
#pragma unroll
  for (int i = 0; i < 16; ++i) acc[i] = make_float4(0.f, 0.f, 0.f, 0.f);
  const int r0 = wg << 4;

  for (int k0 = 0; k0 < ER; k0 += 4) {
    const float4 bv0 = *(const float4*)(Bm + (size_t)(k0 + 0) * D_DIM + c4);
    const float4 bv1 = *(const float4*)(Bm + (size_t)(k0 + 1) * D_DIM + c4);
    const float4 bv2 = *(const float4*)(Bm + (size_t)(k0 + 2) * D_DIM + c4);
    const float4 bv3 = *(const float4*)(Bm + (size_t)(k0 + 3) * D_DIM + c4);
#pragma unroll
    for (int i = 0; i < 16; ++i) {
      float pv[4];
      *(float4*)pv = *(const float4*)&Pl[r0 + i][k0];  // uniform -> broadcast
      acc[i].x = fmaf(pv[0], bv0.x, fmaf(pv[1], bv1.x, fmaf(pv[2], bv2.x, fmaf(pv[3], bv3.x, acc[i].x))));
      acc[i].y = fmaf(pv[0], bv0.y, fmaf(pv[1], bv1.y, fmaf(pv[2], bv2.y, fmaf(pv[3], bv3.y, acc[i].y))));
      acc[i].z = fmaf(pv[0], bv0.z, fmaf(pv[1], bv1.z, fmaf(pv[2], bv2.z, fmaf(pv[3], bv3.z, acc[i].z))));
      acc[i].w = fmaf(pv[0], bv0.w, fmaf(pv[1], bv1.w, fmaf(pv[2], bv2.w, fmaf(pv[3], bv3.w, acc[i].w))));
    }
  }

#pragma unroll
  for (int i = 0; i < 16; ++i) {
    const size_t o = (size_t)(tokb + r0 + i) * D_DIM + c4;
    const float4 b = *(const float4*)(base + o);
    float4 r;
    r.x = acc[i].x + b.x;
    r.y = acc[i].y + b.y;
    r.z = acc[i].z + b.z;
    r.w = acc[i].w + b.w;
    *(float4*)(out + o) = r;
  }
}

// ---------------------------------------------------------------------------
extern "C" void kernel_launch(void* const* d_in, const int* in_sizes, int n_in,
                              void* d_out, int out_size, void* d_ws,
                              size_t ws_size, hipStream_t stream) {
  const float* x  = (const float*)d_in[0];
  const float* bo = (const float*)d_in[1];
  const float* A  = (const float*)d_in[2];
  const float* Bm = (const float*)d_in[3];
  const float* W1 = (const float*)d_in[4];
  const float* b1 = (const float*)d_in[5];
  const float* W2 = (const float*)d_in[6];
  const float* b2 = (const float*)d_in[7];
  float* out = (float*)d_out;

  char* ws = (char*)d_ws;
  float* P = (float*)ws;                                  // [N][80] f32 = 5.25 MiB
  _Float16* Whi = (_Float16*)(ws + 5242880);              // 1.31 MiB
  _Float16* Wlo = (_Float16*)(ws + 5242880 + 1376256);    // 1.31 MiB
  float* logits = (float*)(ws + 5242880 + 2 * 1376256);   // [N][5] = 320 KiB

  pack_w_kernel<<<336, 256, 0, stream>>>(W1, A, Whi, Wlo, logits);
  xgemm_kernel<<<dim3(N_TOK / 64, 3), 256, 0, stream>>>(x, b1, Whi, Wlo, W2,
                                                        logits, P);
  combine_kernel<<<(N_TOK / 64) * (D_DIM / 256), 256, 0, stream>>>(
      P, Bm, bo, logits, b2, out);
}